// Round 1
// baseline (442.757 us; speedup 1.0000x reference)
//
#include <hip/hip_runtime.h>

#define N_NODES 50000
#define E_EDGES 800000
#define F_IN    64
#define F_HID   256
#define F_OUT   64

#define BSZ        64     // nodes per bucket == MLP tile rows
#define NB         782    // ceil(50000/64)
#define CAP        1536   // staging slots per bucket (mean 1024, +16 sigma)
#define CHUNK      4096   // edges per bin block
#define EPB        16     // edges per thread in bin phase
#define BIN_BLOCKS ((E_EDGES + CHUNK - 1) / CHUNK)          // 196
#define X2B_ITEMS  (N_NODES * F_IN / 8)                     // 400000 short8s
#define X2B_BLOCKS ((X2B_ITEMS + 255) / 256)                // 1563
#define SWZ_BLOCKS 16                                       // 16 blocks x 4 tiles = 64 weight tiles

typedef __attribute__((ext_vector_type(8))) short short8;  // 8 bf16 (4 VGPRs)
typedef __attribute__((ext_vector_type(4))) float f32x4;

__device__ inline unsigned short f2bf(float f) {
    unsigned int u = __float_as_uint(f);
    unsigned int r = u + 0x7FFF + ((u >> 16) & 1);   // round-to-nearest-even
    return (unsigned short)(r >> 16);
}
__device__ inline float bflo(unsigned int u) { return __uint_as_float(u << 16); }
__device__ inline float bfhi(unsigned int u) { return __uint_as_float(u & 0xFFFF0000u); }

// ---------- K1: minimal gcur zeroing (must precede pass_a's atomics) ----------
__global__ __launch_bounds__(256) void zero_gcur(int* __restrict__ gcur) {
    for (int i = threadIdx.x; i < NB; i += 256) gcur[i] = 0;
}

// ---------- K2 (fused pass A): bin edges + x->bf16 + weight swizzle ----------
// staging value = ((unsigned)dst<<16) | src; bucket = dst>>6 = packed>>22.
__global__ __launch_bounds__(256) void pass_a(const int* __restrict__ src,
                                              const int* __restrict__ dst,
                                              int* __restrict__ gcur,
                                              unsigned int* __restrict__ staging,
                                              const float* __restrict__ x,
                                              unsigned short* __restrict__ xb,
                                              const float* __restrict__ W1,
                                              const float* __restrict__ W2,
                                              short8* __restrict__ Wp1,
                                              short8* __restrict__ Wp2) {
    if (blockIdx.x >= BIN_BLOCKS + X2B_BLOCKS) {
        // ---- weight swizzle into MFMA B-fragment tiles (64 tiles over 16 blocks) ----
        int t = (blockIdx.x - (BIN_BLOCKS + X2B_BLOCKS)) * 4 + (threadIdx.x >> 6);
        int lane = threadIdx.x & 63;
        int quad = lane >> 4, l16 = lane & 15;
        short8 v;
        if (t < 32) {
            int nb = t >> 1, kb = t & 1;
            #pragma unroll
            for (int j = 0; j < 8; ++j)
                v[j] = (short)f2bf(W1[(kb * 32 + quad * 8 + j) * F_HID + nb * 16 + l16]);
            Wp1[t * 64 + lane] = v;
        } else {
            int u = t - 32;
            int nb = u >> 3, kb = u & 7;
            #pragma unroll
            for (int j = 0; j < 8; ++j)
                v[j] = (short)f2bf(W2[(kb * 32 + quad * 8 + j) * F_OUT + nb * 16 + l16]);
            Wp2[u * 64 + lane] = v;
        }
        return;
    }
    if (blockIdx.x >= BIN_BLOCKS) {
        // ---- x -> bf16 conversion ----
        int idx = (blockIdx.x - BIN_BLOCKS) * 256 + threadIdx.x;
        if (idx < X2B_ITEMS) {
            float4 a = ((const float4*)x)[idx * 2 + 0];
            float4 b = ((const float4*)x)[idx * 2 + 1];
            short8 o;
            o[0] = (short)f2bf(a.x); o[1] = (short)f2bf(a.y);
            o[2] = (short)f2bf(a.z); o[3] = (short)f2bf(a.w);
            o[4] = (short)f2bf(b.x); o[5] = (short)f2bf(b.y);
            o[6] = (short)f2bf(b.z); o[7] = (short)f2bf(b.w);
            ((short8*)xb)[idx] = o;
        }
        return;
    }
    // ---- edge binning ----
    __shared__ int bbase[NB], lcur[NB];
    int tid = threadIdx.x;
    for (int i = tid; i < NB; i += 256) lcur[i] = 0;
    __syncthreads();
    int e0 = blockIdx.x * CHUNK;
    unsigned int myp[EPB];
    int myr[EPB];
    #pragma unroll
    for (int i = 0; i < EPB; ++i) {
        int e = e0 + i * 256 + tid;
        if (e < E_EDGES) {
            unsigned int d = (unsigned int)dst[e];
            unsigned int s = (unsigned int)src[e];
            myp[i] = (d << 16) | s;
            myr[i] = atomicAdd(&lcur[d >> 6], 1);
        }
    }
    __syncthreads();
    for (int i = tid; i < NB; i += 256)
        if (lcur[i] > 0) bbase[i] = atomicAdd(&gcur[i], lcur[i]);
    __syncthreads();
    #pragma unroll
    for (int i = 0; i < EPB; ++i) {
        int e = e0 + i * 256 + tid;
        if (e < E_EDGES) {
            unsigned int b = myp[i] >> 22;           // = dst >> 6 (< 782)
            int pos = bbase[b] + myr[i];
            if (pos < CAP) staging[(size_t)b * CAP + pos] = myp[i];
        }
    }
}

// ---------- K3: edge-parallel LDS-atomic aggregate + fused MLP ----------
// Bucket b's 64 nodes == MLP tile b's 64 rows: agg lives only in LDS (Gf).
__global__ __launch_bounds__(256, 4) void bucket_mlp(
        const int* __restrict__ gcur,
        const unsigned int* __restrict__ staging,
        const unsigned short* __restrict__ xb,
        const float* __restrict__ eps,
        const short8* __restrict__ Wp1,
        const float* __restrict__ b1,
        const short8* __restrict__ Wp2,
        const float* __restrict__ b2,
        float* __restrict__ out) {
    __shared__ float Gf[BSZ][65];                            // 16.6 KB; bank = (row+feat)%32
    __shared__ __align__(16) unsigned short HsW[4][16][40];  // 5.1 KB per-wave H chunk
    int b = blockIdx.x, tid = threadIdx.x;

    // zero the 64x64 accumulator region
    #pragma unroll
    for (int z = 0; z < 16; ++z) {
        int idx = tid + z * 256;
        Gf[idx >> 6][idx & 63] = 0.f;
    }
    __syncthreads();

    int ecnt = gcur[b];
    if (ecnt > CAP) ecnt = CAP;
    const uint4* xv = (const uint4*)xb;
    const unsigned int* stg = staging + (size_t)b * CAP;
    int fi = tid & 3;                                        // 4 lanes per edge, 16 feats each

    // ---- edge-parallel aggregation, 2-deep pipelined (no rank/scan/sort needed) ----
    {
        int i0 = tid >> 2;
        unsigned int p0 = 0, p1 = 0;
        uint4 u0a = {0,0,0,0}, u0b = {0,0,0,0};
        if (i0 < ecnt)      p0 = stg[i0];
        if (i0 + 64 < ecnt) p1 = stg[i0 + 64];
        if (i0 < ecnt) {
            int s = p0 & 0xFFFF;
            u0a = xv[s * 8 + fi * 2 + 0];
            u0b = xv[s * 8 + fi * 2 + 1];
        }
        for (int i = i0; i < ecnt; i += 64) {
            unsigned int p2 = 0;
            if (i + 128 < ecnt) p2 = stg[i + 128];
            uint4 u1a = {0,0,0,0}, u1b = {0,0,0,0};
            if (i + 64 < ecnt) {
                int s1 = p1 & 0xFFFF;
                u1a = xv[s1 * 8 + fi * 2 + 0];
                u1b = xv[s1 * 8 + fi * 2 + 1];
            }
            int d = (p0 >> 16) & (BSZ - 1);
            float* g = &Gf[d][fi * 16];
            atomicAdd(&g[0],  bflo(u0a.x)); atomicAdd(&g[1],  bfhi(u0a.x));
            atomicAdd(&g[2],  bflo(u0a.y)); atomicAdd(&g[3],  bfhi(u0a.y));
            atomicAdd(&g[4],  bflo(u0a.z)); atomicAdd(&g[5],  bfhi(u0a.z));
            atomicAdd(&g[6],  bflo(u0a.w)); atomicAdd(&g[7],  bfhi(u0a.w));
            atomicAdd(&g[8],  bflo(u0b.x)); atomicAdd(&g[9],  bfhi(u0b.x));
            atomicAdd(&g[10], bflo(u0b.y)); atomicAdd(&g[11], bfhi(u0b.y));
            atomicAdd(&g[12], bflo(u0b.z)); atomicAdd(&g[13], bfhi(u0b.z));
            atomicAdd(&g[14], bflo(u0b.w)); atomicAdd(&g[15], bfhi(u0b.w));
            p0 = p1; p1 = p2; u0a = u1a; u0b = u1b;
        }
    }
    __syncthreads();

    // ---- A-fragment build: Gf + (1+eps)*x fused, straight to bf16 frags ----
    int wave = tid >> 6, lane = tid & 63;
    int quad = lane >> 4, l16 = lane & 15;
    int lrow = wave * 16 + l16;                              // local row 0..63
    int n = b * BSZ + lrow;
    int nc = n < N_NODES ? n : N_NODES - 1;                  // clamp: garbage rows discarded
    float sc = 1.0f + eps[0];
    uint4 xq0 = xv[nc * 8 + quad];                           // feats quad*8 .. +7
    uint4 xq1 = xv[nc * 8 + 4 + quad];                       // feats 32+quad*8 .. +7
    const float* gr0 = &Gf[lrow][quad * 8];
    const float* gr1 = &Gf[lrow][32 + quad * 8];
    short8 a0, a1;
    a0[0] = (short)f2bf(gr0[0] + sc * bflo(xq0.x));
    a0[1] = (short)f2bf(gr0[1] + sc * bfhi(xq0.x));
    a0[2] = (short)f2bf(gr0[2] + sc * bflo(xq0.y));
    a0[3] = (short)f2bf(gr0[3] + sc * bfhi(xq0.y));
    a0[4] = (short)f2bf(gr0[4] + sc * bflo(xq0.z));
    a0[5] = (short)f2bf(gr0[5] + sc * bfhi(xq0.z));
    a0[6] = (short)f2bf(gr0[6] + sc * bflo(xq0.w));
    a0[7] = (short)f2bf(gr0[7] + sc * bfhi(xq0.w));
    a1[0] = (short)f2bf(gr1[0] + sc * bflo(xq1.x));
    a1[1] = (short)f2bf(gr1[1] + sc * bfhi(xq1.x));
    a1[2] = (short)f2bf(gr1[2] + sc * bflo(xq1.y));
    a1[3] = (short)f2bf(gr1[3] + sc * bfhi(xq1.y));
    a1[4] = (short)f2bf(gr1[4] + sc * bflo(xq1.z));
    a1[5] = (short)f2bf(gr1[5] + sc * bfhi(xq1.z));
    a1[6] = (short)f2bf(gr1[6] + sc * bflo(xq1.w));
    a1[7] = (short)f2bf(gr1[7] + sc * bfhi(xq1.w));

    // ---- MLP: wave = 16-row stripe; H streamed in 32-col chunks ----
    // HsW[wave] is wave-private: per-wave LDS is in-order, so wave_barrier
    // (zero-cost) replaces the former 16 full-block __syncthreads.
    f32x4 acc2[4];
    #pragma unroll
    for (int ob = 0; ob < 4; ++ob) acc2[ob] = (f32x4){0.f, 0.f, 0.f, 0.f};

    #pragma unroll
    for (int kb = 0; kb < 8; ++kb) {
        f32x4 h0 = {0.f, 0.f, 0.f, 0.f}, h1 = {0.f, 0.f, 0.f, 0.f};
        h0 = __builtin_amdgcn_mfma_f32_16x16x32_bf16(a0, Wp1[((2 * kb + 0) * 2 + 0) * 64 + lane], h0, 0, 0, 0);
        h0 = __builtin_amdgcn_mfma_f32_16x16x32_bf16(a1, Wp1[((2 * kb + 0) * 2 + 1) * 64 + lane], h0, 0, 0, 0);
        h1 = __builtin_amdgcn_mfma_f32_16x16x32_bf16(a0, Wp1[((2 * kb + 1) * 2 + 0) * 64 + lane], h1, 0, 0, 0);
        h1 = __builtin_amdgcn_mfma_f32_16x16x32_bf16(a1, Wp1[((2 * kb + 1) * 2 + 1) * 64 + lane], h1, 0, 0, 0);
        float bias0 = b1[(2 * kb + 0) * 16 + l16];
        float bias1 = b1[(2 * kb + 1) * 16 + l16];
        #pragma unroll
        for (int i = 0; i < 4; ++i) {
            HsW[wave][quad * 4 + i][l16]      = f2bf(h0[i] + bias0);
            HsW[wave][quad * 4 + i][16 + l16] = f2bf(h1[i] + bias1);
        }
        __builtin_amdgcn_sched_barrier(0);
        __builtin_amdgcn_wave_barrier();
        __builtin_amdgcn_sched_barrier(0);
        short8 af = *(const short8*)&HsW[wave][l16][quad * 8];
        #pragma unroll
        for (int ob = 0; ob < 4; ++ob)
            acc2[ob] = __builtin_amdgcn_mfma_f32_16x16x32_bf16(af, Wp2[(ob * 8 + kb) * 64 + lane], acc2[ob], 0, 0, 0);
        __builtin_amdgcn_sched_barrier(0);
        __builtin_amdgcn_wave_barrier();
        __builtin_amdgcn_sched_barrier(0);
    }

    #pragma unroll
    for (int ob = 0; ob < 4; ++ob) {
        int col = ob * 16 + l16;
        float bias = b2[col];
        #pragma unroll
        for (int i = 0; i < 4; ++i) {
            int grow = b * BSZ + wave * 16 + quad * 4 + i;
            if (grow < N_NODES) out[grow * F_OUT + col] = acc2[ob][i] + bias;
        }
    }
}

extern "C" void kernel_launch(void* const* d_in, const int* in_sizes, int n_in,
                              void* d_out, int out_size, void* d_ws, size_t ws_size,
                              hipStream_t stream) {
    const float* x   = (const float*)d_in[0];
    const float* W1  = (const float*)d_in[1];
    const float* b1  = (const float*)d_in[2];
    const float* W2  = (const float*)d_in[3];
    const float* b2  = (const float*)d_in[4];
    const float* eps = (const float*)d_in[5];
    const int*   src = (const int*)d_in[6];
    const int*   dst = (const int*)d_in[7];
    float* out = (float*)d_out;

    // ws layout (bytes):
    //   0x0000000 xb       bf16 [50000][64] (6.40 MB)
    //   0x0700000 gcur     (782 int)
    //   0x0710000 Wp1 (32K) | 0x0718000 Wp2 (32K)
    //   0x0800000 staging  u32 [782*1536]   (4.80 MB)
    char* base = (char*)d_ws;
    unsigned short* xb = (unsigned short*)base;
    int* gcur        = (int*)(base + 0x700000);
    short8* Wp1      = (short8*)(base + 0x710000);
    short8* Wp2      = (short8*)(base + 0x718000);
    unsigned int* staging = (unsigned int*)(base + 0x800000);

    zero_gcur<<<1, 256, 0, stream>>>(gcur);
    pass_a<<<BIN_BLOCKS + X2B_BLOCKS + SWZ_BLOCKS, 256, 0, stream>>>(
        src, dst, gcur, staging, x, xb, W1, W2, Wp1, Wp2);
    bucket_mlp<<<NB, 256, 0, stream>>>(gcur, staging, xb, eps, Wp1, b1, Wp2, b2, out);
}

// Round 2
// 122.909 us; speedup vs baseline: 3.6023x; 3.6023x over previous
//
#include <hip/hip_runtime.h>

#define N_NODES 50000
#define E_EDGES 800000
#define F_IN    64
#define F_HID   256
#define F_OUT   64

#define BSZ        64     // nodes per bucket == MLP tile rows
#define NB         782    // ceil(50000/64)
#define CAP        1536   // staging slots per bucket (mean 1024, +16 sigma)
#define CHUNK      4096   // edges per bin block
#define EPB        16     // edges per thread in bin phase
#define BIN_BLOCKS ((E_EDGES + CHUNK - 1) / CHUNK)          // 196
#define X2B_ITEMS  (N_NODES * F_IN / 8)                     // 400000 short8s
#define X2B_BLOCKS ((X2B_ITEMS + 255) / 256)                // 1563
#define SWZ_BLOCKS 16                                       // 16 blocks x 4 tiles = 64 weight tiles

typedef __attribute__((ext_vector_type(8))) short short8;  // 8 bf16 (4 VGPRs)
typedef __attribute__((ext_vector_type(4))) float f32x4;

__device__ inline unsigned short f2bf(float f) {
    unsigned int u = __float_as_uint(f);
    unsigned int r = u + 0x7FFF + ((u >> 16) & 1);   // round-to-nearest-even
    return (unsigned short)(r >> 16);
}
__device__ inline float bflo(unsigned int u) { return __uint_as_float(u << 16); }
__device__ inline float bfhi(unsigned int u) { return __uint_as_float(u & 0xFFFF0000u); }

// ---------- K1: minimal gcur zeroing (must precede pass_a's atomics) ----------
__global__ __launch_bounds__(256) void zero_gcur(int* __restrict__ gcur) {
    for (int i = threadIdx.x; i < NB; i += 256) gcur[i] = 0;
}

// ---------- K2 (fused pass A): bin edges + x->bf16 + weight swizzle ----------
// staging value = ((unsigned)dst<<16) | src; bucket = dst>>6 = packed>>22.
__global__ __launch_bounds__(256) void pass_a(const int* __restrict__ src,
                                              const int* __restrict__ dst,
                                              int* __restrict__ gcur,
                                              unsigned int* __restrict__ staging,
                                              const float* __restrict__ x,
                                              unsigned short* __restrict__ xb,
                                              const float* __restrict__ W1,
                                              const float* __restrict__ W2,
                                              short8* __restrict__ Wp1,
                                              short8* __restrict__ Wp2) {
    if (blockIdx.x >= BIN_BLOCKS + X2B_BLOCKS) {
        // ---- weight swizzle into MFMA B-fragment tiles (64 tiles over 16 blocks) ----
        int t = (blockIdx.x - (BIN_BLOCKS + X2B_BLOCKS)) * 4 + (threadIdx.x >> 6);
        int lane = threadIdx.x & 63;
        int quad = lane >> 4, l16 = lane & 15;
        short8 v;
        if (t < 32) {
            int nb = t >> 1, kb = t & 1;
            #pragma unroll
            for (int j = 0; j < 8; ++j)
                v[j] = (short)f2bf(W1[(kb * 32 + quad * 8 + j) * F_HID + nb * 16 + l16]);
            Wp1[t * 64 + lane] = v;
        } else {
            int u = t - 32;
            int nb = u >> 3, kb = u & 7;
            #pragma unroll
            for (int j = 0; j < 8; ++j)
                v[j] = (short)f2bf(W2[(kb * 32 + quad * 8 + j) * F_OUT + nb * 16 + l16]);
            Wp2[u * 64 + lane] = v;
        }
        return;
    }
    if (blockIdx.x >= BIN_BLOCKS) {
        // ---- x -> bf16 conversion ----
        int idx = (blockIdx.x - BIN_BLOCKS) * 256 + threadIdx.x;
        if (idx < X2B_ITEMS) {
            float4 a = ((const float4*)x)[idx * 2 + 0];
            float4 b = ((const float4*)x)[idx * 2 + 1];
            short8 o;
            o[0] = (short)f2bf(a.x); o[1] = (short)f2bf(a.y);
            o[2] = (short)f2bf(a.z); o[3] = (short)f2bf(a.w);
            o[4] = (short)f2bf(b.x); o[5] = (short)f2bf(b.y);
            o[6] = (short)f2bf(b.z); o[7] = (short)f2bf(b.w);
            ((short8*)xb)[idx] = o;
        }
        return;
    }
    // ---- edge binning ----
    __shared__ int bbase[NB], lcur[NB];
    int tid = threadIdx.x;
    for (int i = tid; i < NB; i += 256) lcur[i] = 0;
    __syncthreads();
    int e0 = blockIdx.x * CHUNK;
    unsigned int myp[EPB];
    int myr[EPB];
    #pragma unroll
    for (int i = 0; i < EPB; ++i) {
        int e = e0 + i * 256 + tid;
        if (e < E_EDGES) {
            unsigned int d = (unsigned int)dst[e];
            unsigned int s = (unsigned int)src[e];
            myp[i] = (d << 16) | s;
            myr[i] = atomicAdd(&lcur[d >> 6], 1);
        }
    }
    __syncthreads();
    for (int i = tid; i < NB; i += 256)
        if (lcur[i] > 0) bbase[i] = atomicAdd(&gcur[i], lcur[i]);
    __syncthreads();
    #pragma unroll
    for (int i = 0; i < EPB; ++i) {
        int e = e0 + i * 256 + tid;
        if (e < E_EDGES) {
            unsigned int b = myp[i] >> 22;           // = dst >> 6 (< 782)
            int pos = bbase[b] + myr[i];
            if (pos < CAP) staging[(size_t)b * CAP + pos] = myp[i];
        }
    }
}

// ---------- K3: fused rank + reorder + gather + MLP (one 256-thread block/bucket) ----------
// Bucket b's 64 nodes == MLP tile b's 64 rows: agg lives only in LDS (Gs).
// Aggregation is the deterministic rank/reorder/gather pipeline (int LDS atomics
// only — f32 LDS atomicAdd lowers to a CAS loop on gfx950 and is catastrophic).
__global__ __launch_bounds__(256, 4) void bucket_mlp(
        const int* __restrict__ gcur,
        const unsigned int* __restrict__ staging,
        const unsigned short* __restrict__ xb,
        const float* __restrict__ eps,
        const short8* __restrict__ Wp1,
        const float* __restrict__ b1,
        const short8* __restrict__ Wp2,
        const float* __restrict__ b2,
        float* __restrict__ out) {
    __shared__ int lcnt[BSZ], loff[BSZ];
    __shared__ unsigned short obuf[CAP];                     // 3 KB
    __shared__ __align__(16) unsigned short Gs[BSZ][72];     // 9.2 KB
    __shared__ __align__(16) unsigned short HsW[4][16][40];  // 5.1 KB per-wave H chunk
    int b = blockIdx.x, tid = threadIdx.x;
    if (tid < BSZ) lcnt[tid] = 0;
    __syncthreads();
    int ecnt = gcur[b];
    if (ecnt > CAP) ecnt = CAP;
    // rank: 6 edges per thread (6*256 = 1536 = CAP); int LDS atomics are native
    unsigned int mp[6];
    int mr[6];
    #pragma unroll
    for (int k = 0; k < 6; ++k) {
        int i = tid + k * 256;
        if (i < ecnt) {
            unsigned int p = staging[(size_t)b * CAP + i];
            mp[k] = p;
            mr[k] = atomicAdd(&lcnt[(p >> 16) & (BSZ - 1)], 1);
        }
    }
    __syncthreads();
    // single-wave shfl inclusive scan over the 64 counts (replaces 12-barrier scan)
    if (tid < BSZ) {
        int v = lcnt[tid];
        int s = v;
        #pragma unroll
        for (int off = 1; off < 64; off <<= 1) {
            int u = __shfl_up(s, off, 64);
            if (tid >= off) s += u;
        }
        loff[tid] = s - v;
    }
    __syncthreads();
    #pragma unroll
    for (int k = 0; k < 6; ++k) {
        int i = tid + k * 256;
        if (i < ecnt) {
            int d = (mp[k] >> 16) & (BSZ - 1);
            obuf[loff[d] + mr[k]] = (unsigned short)(mp[k] & 0xFFFFu);
        }
    }
    __syncthreads();

    // ---- gather: 4 lanes per node (lane owns 16 feats = 2 uint4) ----
    {
        int nl = tid >> 2;
        int fi = tid & 3;
        int n = b * BSZ + nl;
        float acc[16] = {};
        if (n < N_NODES) {
            const uint4* xv = (const uint4*)xb;
            int start = loff[nl];
            int cnt   = lcnt[nl];
            int j = 0;
            for (; j + 2 <= cnt; j += 2) {
                int s0 = obuf[start + j + 0];
                int s1 = obuf[start + j + 1];
                uint4 u0 = xv[s0 * 8 + fi * 2 + 0];
                uint4 u1 = xv[s0 * 8 + fi * 2 + 1];
                uint4 u2 = xv[s1 * 8 + fi * 2 + 0];
                uint4 u3 = xv[s1 * 8 + fi * 2 + 1];
                acc[0] += bflo(u0.x); acc[1] += bfhi(u0.x);
                acc[2] += bflo(u0.y); acc[3] += bfhi(u0.y);
                acc[4] += bflo(u0.z); acc[5] += bfhi(u0.z);
                acc[6] += bflo(u0.w); acc[7] += bfhi(u0.w);
                acc[8]  += bflo(u1.x); acc[9]  += bfhi(u1.x);
                acc[10] += bflo(u1.y); acc[11] += bfhi(u1.y);
                acc[12] += bflo(u1.z); acc[13] += bfhi(u1.z);
                acc[14] += bflo(u1.w); acc[15] += bfhi(u1.w);
                acc[0] += bflo(u2.x); acc[1] += bfhi(u2.x);
                acc[2] += bflo(u2.y); acc[3] += bfhi(u2.y);
                acc[4] += bflo(u2.z); acc[5] += bfhi(u2.z);
                acc[6] += bflo(u2.w); acc[7] += bfhi(u2.w);
                acc[8]  += bflo(u3.x); acc[9]  += bfhi(u3.x);
                acc[10] += bflo(u3.y); acc[11] += bfhi(u3.y);
                acc[12] += bflo(u3.z); acc[13] += bfhi(u3.z);
                acc[14] += bflo(u3.w); acc[15] += bfhi(u3.w);
            }
            if (j < cnt) {
                int s0 = obuf[start + j];
                uint4 u0 = xv[s0 * 8 + fi * 2 + 0];
                uint4 u1 = xv[s0 * 8 + fi * 2 + 1];
                acc[0] += bflo(u0.x); acc[1] += bfhi(u0.x);
                acc[2] += bflo(u0.y); acc[3] += bfhi(u0.y);
                acc[4] += bflo(u0.z); acc[5] += bfhi(u0.z);
                acc[6] += bflo(u0.w); acc[7] += bfhi(u0.w);
                acc[8]  += bflo(u1.x); acc[9]  += bfhi(u1.x);
                acc[10] += bflo(u1.y); acc[11] += bfhi(u1.y);
                acc[12] += bflo(u1.z); acc[13] += bfhi(u1.z);
                acc[14] += bflo(u1.w); acc[15] += bfhi(u1.w);
            }
            float sc = 1.0f + eps[0];
            uint4 m0 = xv[n * 8 + fi * 2 + 0];
            uint4 m1 = xv[n * 8 + fi * 2 + 1];
            acc[0] += sc * bflo(m0.x); acc[1] += sc * bfhi(m0.x);
            acc[2] += sc * bflo(m0.y); acc[3] += sc * bfhi(m0.y);
            acc[4] += sc * bflo(m0.z); acc[5] += sc * bfhi(m0.z);
            acc[6] += sc * bflo(m0.w); acc[7] += sc * bfhi(m0.w);
            acc[8]  += sc * bflo(m1.x); acc[9]  += sc * bfhi(m1.x);
            acc[10] += sc * bflo(m1.y); acc[11] += sc * bfhi(m1.y);
            acc[12] += sc * bflo(m1.z); acc[13] += sc * bfhi(m1.z);
            acc[14] += sc * bflo(m1.w); acc[15] += sc * bfhi(m1.w);
        }
        short8 o0, o1;
        #pragma unroll
        for (int k = 0; k < 8; ++k) { o0[k] = (short)f2bf(acc[k]); o1[k] = (short)f2bf(acc[8 + k]); }
        *(short8*)&Gs[nl][fi * 16 + 0] = o0;
        *(short8*)&Gs[nl][fi * 16 + 8] = o1;
    }
    __syncthreads();

    // ---- MLP from Gs: wave = 16-row stripe; H streamed in 32-col chunks ----
    // HsW[wave] is wave-private: per-wave LDS is in-order, so wave_barrier
    // (zero-cost) replaces the former 16 full-block __syncthreads.
    int wave = tid >> 6, lane = tid & 63;
    int quad = lane >> 4, l16 = lane & 15;
    short8 a0 = *(const short8*)&Gs[wave * 16 + l16][quad * 8];
    short8 a1 = *(const short8*)&Gs[wave * 16 + l16][32 + quad * 8];

    f32x4 acc2[4];
    #pragma unroll
    for (int ob = 0; ob < 4; ++ob) acc2[ob] = (f32x4){0.f, 0.f, 0.f, 0.f};

    #pragma unroll
    for (int kb = 0; kb < 8; ++kb) {
        f32x4 h0 = {0.f, 0.f, 0.f, 0.f}, h1 = {0.f, 0.f, 0.f, 0.f};
        h0 = __builtin_amdgcn_mfma_f32_16x16x32_bf16(a0, Wp1[((2 * kb + 0) * 2 + 0) * 64 + lane], h0, 0, 0, 0);
        h0 = __builtin_amdgcn_mfma_f32_16x16x32_bf16(a1, Wp1[((2 * kb + 0) * 2 + 1) * 64 + lane], h0, 0, 0, 0);
        h1 = __builtin_amdgcn_mfma_f32_16x16x32_bf16(a0, Wp1[((2 * kb + 1) * 2 + 0) * 64 + lane], h1, 0, 0, 0);
        h1 = __builtin_amdgcn_mfma_f32_16x16x32_bf16(a1, Wp1[((2 * kb + 1) * 2 + 1) * 64 + lane], h1, 0, 0, 0);
        float bias0 = b1[(2 * kb + 0) * 16 + l16];
        float bias1 = b1[(2 * kb + 1) * 16 + l16];
        #pragma unroll
        for (int i = 0; i < 4; ++i) {
            HsW[wave][quad * 4 + i][l16]      = f2bf(h0[i] + bias0);
            HsW[wave][quad * 4 + i][16 + l16] = f2bf(h1[i] + bias1);
        }
        __builtin_amdgcn_sched_barrier(0);
        __builtin_amdgcn_wave_barrier();
        __builtin_amdgcn_sched_barrier(0);
        short8 af = *(const short8*)&HsW[wave][l16][quad * 8];
        #pragma unroll
        for (int ob = 0; ob < 4; ++ob)
            acc2[ob] = __builtin_amdgcn_mfma_f32_16x16x32_bf16(af, Wp2[(ob * 8 + kb) * 64 + lane], acc2[ob], 0, 0, 0);
        __builtin_amdgcn_sched_barrier(0);
        __builtin_amdgcn_wave_barrier();
        __builtin_amdgcn_sched_barrier(0);
    }

    #pragma unroll
    for (int ob = 0; ob < 4; ++ob) {
        int col = ob * 16 + l16;
        float bias = b2[col];
        #pragma unroll
        for (int i = 0; i < 4; ++i) {
            int row = b * BSZ + wave * 16 + quad * 4 + i;
            if (row < N_NODES) out[row * F_OUT + col] = acc2[ob][i] + bias;
        }
    }
}

extern "C" void kernel_launch(void* const* d_in, const int* in_sizes, int n_in,
                              void* d_out, int out_size, void* d_ws, size_t ws_size,
                              hipStream_t stream) {
    const float* x   = (const float*)d_in[0];
    const float* W1  = (const float*)d_in[1];
    const float* b1  = (const float*)d_in[2];
    const float* W2  = (const float*)d_in[3];
    const float* b2  = (const float*)d_in[4];
    const float* eps = (const float*)d_in[5];
    const int*   src = (const int*)d_in[6];
    const int*   dst = (const int*)d_in[7];
    float* out = (float*)d_out;

    // ws layout (bytes):
    //   0x0000000 xb       bf16 [50000][64] (6.40 MB)
    //   0x0700000 gcur     (782 int)
    //   0x0710000 Wp1 (32K) | 0x0718000 Wp2 (32K)
    //   0x0800000 staging  u32 [782*1536]   (4.80 MB)
    char* base = (char*)d_ws;
    unsigned short* xb = (unsigned short*)base;
    int* gcur        = (int*)(base + 0x700000);
    short8* Wp1      = (short8*)(base + 0x710000);
    short8* Wp2      = (short8*)(base + 0x718000);
    unsigned int* staging = (unsigned int*)(base + 0x800000);

    zero_gcur<<<1, 256, 0, stream>>>(gcur);
    pass_a<<<BIN_BLOCKS + X2B_BLOCKS + SWZ_BLOCKS, 256, 0, stream>>>(
        src, dst, gcur, staging, x, xb, W1, W2, Wp1, Wp2);
    bucket_mlp<<<NB, 256, 0, stream>>>(gcur, staging, xb, eps, Wp1, b1, Wp2, b2, out);
}